// Round 2
// baseline (240.697 us; speedup 1.0000x reference)
//
#include <hip/hip_runtime.h>

// Problem constants (fixed by reference)
#define CC 32
#define HH 256
#define WW 512
#define NN 4
#define MAXD 48

// Tiling: 256-wide w chunk per block, r-only LDS, 4w x 24d register tile.
#define WT 256
#define RW (WT + MAXD)    // 304 r columns staged (w0-48 .. w0+255)
#define DTILE 24          // d per thread; d0 in {0,24} (mult of 8 -> aligned window)
#define WTILE 4           // w per thread; wb mult of 4 -> aligned float4
// block = 128 threads = 64 w-groups x 2 d-groups
// LDS = 32*304*4 = 38912 B -> 4 blocks/CU (155648 <= 163840), 8 waves/CU

__global__ __launch_bounds__(128, 2)
void cost_volume_kernel(const float* __restrict__ L,
                        const float* __restrict__ R,
                        float* __restrict__ out)
{
    __shared__ float r_s[CC][RW];        // 38 KB, r only; l stays in global/regs

    const int t  = threadIdx.x;          // 0..127
    const int w0 = blockIdx.x * WT;      // 0 or 256
    const int h  = blockIdx.y;
    const int n  = blockIdx.z;

    const size_t chw  = (size_t)HH * WW;                  // channel stride
    const size_t rowB = (size_t)n * CC * chw + (size_t)h * WW;  // (n, c=0, h, 0)

    // ---- stage r: 32 rows x 304 floats = 2432 float4, 19 per thread, coalesced
    #pragma unroll
    for (int k = 0; k < 19; ++k) {
        int idx = t + 128 * k;           // 0..2431
        int c   = idx / 76;              // 76 float4 per row
        int j4  = idx - c * 76;
        int g   = w0 - MAXD + 4 * j4;    // global w of this float4 (max 508, +3 ok)
        float4 v = make_float4(0.f, 0.f, 0.f, 0.f);
        if (g >= 0)                      // w<0 -> zeros (implements zero pad / w<d)
            v = *(const float4*)(R + rowB + (size_t)c * chw + g);
        *(float4*)&r_s[c][4 * j4] = v;
    }
    __syncthreads();                     // single barrier per block

    const int wg = t & 63;               // wave0: dg=0, wave1: dg=1 (wave-uniform d0)
    const int dg = t >> 6;
    const int wb = wg * WTILE;           // 0..252, multiple of 4
    const int d0 = dg * DTILE;           // 0 or 24
    // r_s col for (local w, d) is lw + 48 - d; needed [wb+25-d0, wb+51-d0];
    // aligned 28-float superset starts at:
    const int jA = wb + 24 - d0;         // multiple of 4; 0..276, +27 <= 303

    float acc[DTILE][WTILE];
    #pragma unroll
    for (int k = 0; k < DTILE; ++k)
        #pragma unroll
        for (int i = 0; i < WTILE; ++i)
            acc[k][i] = 0.f;

    const float* lp = L + rowB + w0 + wb;    // + c*chw each iteration, aligned
    float4 lv = *(const float4*)lp;          // prefetch c=0
    for (int c = 0; c < CC; ++c) {
        float4 lnext;
        if (c + 1 < CC)                      // uniform branch, no divergence
            lnext = *(const float4*)(lp + (size_t)(c + 1) * chw);
        float rv[28];
        #pragma unroll
        for (int q = 0; q < 7; ++q)
            *(float4*)&rv[4 * q] = *(const float4*)&r_s[c][jA + 4 * q];
        const float lf[4] = {lv.x, lv.y, lv.z, lv.w};
        #pragma unroll
        for (int k = 0; k < DTILE; ++k)
            #pragma unroll
            for (int i = 0; i < WTILE; ++i)
                acc[k][i] += lf[i] * rv[24 + i - k];   // offsets 1..27, compile-time
        lv = lnext;
    }

    const float inv = 1.0f / 32.0f;      // mean over C, exact pow2
    #pragma unroll
    for (int k = 0; k < DTILE; ++k) {
        const int d = d0 + k;
        float4 o = make_float4(acc[k][0] * inv, acc[k][1] * inv,
                               acc[k][2] * inv, acc[k][3] * inv);
        *(float4*)(out + (((size_t)n * MAXD + d) * HH + h) * WW + w0 + wb) = o;
    }
}

extern "C" void kernel_launch(void* const* d_in, const int* in_sizes, int n_in,
                              void* d_out, int out_size, void* d_ws, size_t ws_size,
                              hipStream_t stream) {
    const float* L = (const float*)d_in[0];
    const float* R = (const float*)d_in[1];
    float* out = (float*)d_out;
    // d_in[2] (use_naive) is ignored per reference.
    dim3 grid(WW / WT, HH, NN);          // 2 x 256 x 4 = 2048 blocks
    cost_volume_kernel<<<grid, dim3(128, 1, 1), 0, stream>>>(L, R, out);
}

// Round 3
// 211.444 us; speedup vs baseline: 1.1383x; 1.1383x over previous
//
#include <hip/hip_runtime.h>

// Problem constants (fixed by reference)
#define CC 32
#define HH 256
#define WW 512
#define NN 4
#define MAXD 48

// Tiling: 256-wide w chunk, r-only LDS, 256-thread blocks (4 waves),
// per-thread 4w x 12d register tile.
#define WT 256
#define RW (WT + MAXD)    // 304 r columns staged (w0-48 .. w0+255)
#define DTILE 12          // d per thread; d0 = 12*dg (mult of 4 -> aligned window)
#define WTILE 4           // w per thread; wb mult of 4 -> aligned float4
// block = 256 threads = 64 w-groups x 4 d-groups (dg wave-uniform: dg = t>>6)
// LDS = 32*304*4 = 38912 B -> 4 blocks/CU -> 16 waves/CU (4 waves/SIMD, 50% occ)

__global__ __launch_bounds__(256, 4)
void cost_volume_kernel(const float* __restrict__ L,
                        const float* __restrict__ R,
                        float* __restrict__ out)
{
    __shared__ float r_s[CC][RW];        // 38 KB, r only; l stays in global/regs

    const int t  = threadIdx.x;          // 0..255
    const int w0 = blockIdx.x * WT;      // 0 or 256
    const int h  = blockIdx.y;
    const int n  = blockIdx.z;

    const size_t chw  = (size_t)HH * WW;                       // channel stride
    const size_t rowB = (size_t)n * CC * chw + (size_t)h * WW; // (n, c=0, h, 0)

    // ---- stage r: 32 rows x 304 floats = 2432 float4, ~9.5 per thread, coalesced
    #pragma unroll
    for (int k = 0; k < 10; ++k) {
        int idx = t + 256 * k;           // 0..2559
        if (idx < 2432) {
            int c   = idx / 76;          // 76 float4 per row
            int j4  = idx - c * 76;
            int g   = w0 - MAXD + 4 * j4;    // global w of this float4
            float4 v = make_float4(0.f, 0.f, 0.f, 0.f);
            if (g >= 0)                  // w<0 -> zeros (zero pad / w<d)
                v = *(const float4*)(R + rowB + (size_t)c * chw + g);
            *(float4*)&r_s[c][4 * j4] = v;
        }
    }
    __syncthreads();                     // single barrier per block

    const int wg = t & 63;               // dg wave-uniform
    const int dg = t >> 6;               // 0..3
    const int wb = wg * WTILE;           // 0..252, multiple of 4
    const int d0 = dg * DTILE;           // 0,12,24,36
    // r_s col for (local w, d) is lw + 48 - d; needed [wb+37-d0, wb+51-d0];
    // aligned 16-float superset starts at:
    const int jA = wb + 36 - d0;         // multiple of 4; 0..288, +15 <= 303

    float acc[DTILE][WTILE];
    #pragma unroll
    for (int k = 0; k < DTILE; ++k)
        #pragma unroll
        for (int i = 0; i < WTILE; ++i)
            acc[k][i] = 0.f;

    const float* lp = L + rowB + w0 + wb;     // + c*chw per channel, aligned
    float4 lv0 = *(const float4*)(lp);        // 2-deep prefetch
    float4 lv1 = *(const float4*)(lp + chw);
    for (int c = 0; c < CC; ++c) {
        float4 lnext;
        if (c + 2 < CC)                       // uniform branch
            lnext = *(const float4*)(lp + (size_t)(c + 2) * chw);
        float rv[16];
        #pragma unroll
        for (int q = 0; q < 4; ++q)
            *(float4*)&rv[4 * q] = *(const float4*)&r_s[c][jA + 4 * q];
        const float lf[4] = {lv0.x, lv0.y, lv0.z, lv0.w};
        #pragma unroll
        for (int k = 0; k < DTILE; ++k)
            #pragma unroll
            for (int i = 0; i < WTILE; ++i)
                acc[k][i] += lf[i] * rv[12 + i - k];   // offsets 1..15, compile-time
        lv0 = lv1;
        lv1 = lnext;
    }

    const float inv = 1.0f / 32.0f;      // mean over C, exact pow2
    #pragma unroll
    for (int k = 0; k < DTILE; ++k) {
        const int d = d0 + k;
        float4 o = make_float4(acc[k][0] * inv, acc[k][1] * inv,
                               acc[k][2] * inv, acc[k][3] * inv);
        *(float4*)(out + (((size_t)n * MAXD + d) * HH + h) * WW + w0 + wb) = o;
    }
}

extern "C" void kernel_launch(void* const* d_in, const int* in_sizes, int n_in,
                              void* d_out, int out_size, void* d_ws, size_t ws_size,
                              hipStream_t stream) {
    const float* L = (const float*)d_in[0];
    const float* R = (const float*)d_in[1];
    float* out = (float*)d_out;
    // d_in[2] (use_naive) is ignored per reference.
    dim3 grid(WW / WT, HH, NN);          // 2 x 256 x 4 = 2048 blocks
    cost_volume_kernel<<<grid, dim3(256, 1, 1), 0, stream>>>(L, R, out);
}